// Round 12
// baseline (318.044 us; speedup 1.0000x reference)
//
#include <hip/hip_runtime.h>
#include <math.h>

#define B_    4
#define CIN_  32
#define COUT_ 64
#define H_    192
#define W_    192
#define HW_   (H_ * W_)        // 36864
#define NPIX_ (B_ * HW_)       // 147456
#define EPS_  1e-5f

// XCD-aware swizzle (proven R7: FETCH 300->15.5 MB): XCD k owns a
// contiguous half-image-plane.
static __device__ __forceinline__ int swz1152(int blk) {
    return ((blk & 7) * 144) + (blk >> 3);
}
static __device__ __forceinline__ int swz2304(int blk) {
    return ((blk & 7) * 288) + (blk >> 3);
}

struct Cr { int o00, o01, o10, o11; float w00, w01, w10, w11; };

// ---------------------------------------------------------------------------
// Kernel 0: fused prep. Blocks [0,576): transpose x (NCHW) -> xt (NHWC).
// Blocks [576,673): weight transposes + stats zeroing.
// wt_def[kk][c][o64]; wt_off [kk][o20][c32] (o>=18 zero).
// ---------------------------------------------------------------------------
__global__ __launch_bounds__(256) void k_pre(
    const float* __restrict__ x, const float* __restrict__ w_def,
    const float* __restrict__ w_off, float* __restrict__ xt,
    float* __restrict__ wt_def, float* __restrict__ wt_off,
    float* __restrict__ stats)
{
    if (blockIdx.x < NPIX_ / 256) {
        const int pid = blockIdx.x * 256 + threadIdx.x;
        const int b   = pid / HW_;
        const int rem = pid - b * HW_;
        const float* xb = x + (size_t)b * CIN_ * HW_ + rem;
        float4 v[8];
#pragma unroll
        for (int j = 0; j < 8; ++j) {
            v[j].x = xb[(j * 4 + 0) * HW_];
            v[j].y = xb[(j * 4 + 1) * HW_];
            v[j].z = xb[(j * 4 + 2) * HW_];
            v[j].w = xb[(j * 4 + 3) * HW_];
        }
        float4* dst = (float4*)(xt + (size_t)pid * 32);
#pragma unroll
        for (int j = 0; j < 8; ++j) dst[j] = v[j];
    } else {
        const int i = (blockIdx.x - NPIX_ / 256) * 256 + threadIdx.x;
        if (i < 18432) {                       // wt_def[kk][c][o64]
            const int o  = i & 63;
            const int c  = (i >> 6) & 31;
            const int kk = i >> 11;
            wt_def[i] = w_def[(o * 32 + c) * 9 + kk];
        } else if (i < 18432 + 5760) {         // wt_off[kk][o20][c32]
            const int e  = i - 18432;
            const int c  = e & 31;
            const int t  = e >> 5;
            const int o  = t % 20;
            const int kk = t / 20;
            wt_off[e] = (o < 18) ? w_off[(o * 32 + c) * 9 + kk] : 0.f;
        } else if (i < 18432 + 5760 + 512) {
            stats[i - 18432 - 5760] = 0.f;     // sum_bc + sumsq_bc
        }
    }
}

// ---------------------------------------------------------------------------
// Kernel 1: offsets conv (32 -> 18 ch) via LDS x-tile (REGULAR stencil ->
// zero scattered gathers). Block = 256 thr handles 64 px (192 = 3*64, so a
// chunk never straddles a row). Tile = 3 rows x 66 px x 32 ch as
// tile[j][r*66+cc] float4 planes (25.3 KB), loaded fully coalesced.
// Compute: px = tid&63, og = tid>>6 (UNIFORM -> s_load weights), 5 outputs
// per thread over 32 LDS channels x 9 taps; LDS reads lane-stride 16 B
// (conflict-free).
// ---------------------------------------------------------------------------
__global__ __launch_bounds__(256, 6) void k_conv_off(
    const float* __restrict__ xt, const float* __restrict__ wt,
    const float* __restrict__ b_off, float* __restrict__ offs)
{
    __shared__ float4 tile[8][198];            // [ch-quad j][r*66+cc]
    const int tid = threadIdx.x;
    const int px  = tid & 63;
    const int og  = __builtin_amdgcn_readfirstlane(tid >> 6);

    const int blk  = swz2304(blockIdx.x);
    const int base = blk * 64;
    const int b    = base / HW_;
    const int rem0 = base - b * HW_;
    const int h0   = rem0 / W_;
    const int w0   = rem0 - h0 * W_;           // 0, 64, or 128

    // tile load: 1584 float4 (j = i&7 -> consecutive threads read one px's
    // 128 B contiguously from global).
    const float* xb = xt + (size_t)b * HW_ * 32;
    for (int i = tid; i < 1584; i += 256) {
        const int j   = i & 7;
        const int rec = i >> 3;
        const int r   = rec / 66;
        const int cc  = rec - r * 66;
        const int hc  = min(max(h0 + r - 1, 0), H_ - 1);
        const int wc  = min(max(w0 + cc - 1, 0), W_ - 1);
        tile[j][rec] = *(const float4*)(xb + (hc * W_ + wc) * 32 + j * 4);
    }
    __syncthreads();

    const bool rv0 = (h0 - 1 >= 0), rv2 = (h0 + 1 < H_);
    float acc[5] = {0.f, 0.f, 0.f, 0.f, 0.f};

#pragma unroll 1
    for (int kk = 0; kk < 9; ++kk) {
        const int ky = kk / 3, kx = kk % 3;
        const bool rok = (ky == 0) ? rv0 : ((ky == 2) ? rv2 : true);
        const int wcol = w0 + px + kx - 1;
        const float g = (rok && wcol >= 0 && wcol < W_) ? 1.f : 0.f;
        const int rec = ky * 66 + px + kx;

        float4 v[8];
#pragma unroll
        for (int j = 0; j < 8; ++j) {
            v[j] = tile[j][rec];
            v[j].x *= g; v[j].y *= g; v[j].z *= g; v[j].w *= g;
        }
        const float* wk = wt + (kk * 20 + og * 5) * 32;   // [kk][5og..][c32]
#pragma unroll
        for (int oo = 0; oo < 5; ++oo) {
            const float4* wr = (const float4*)(wk + oo * 32);
            float s = acc[oo];
#pragma unroll
            for (int j = 0; j < 8; ++j) {
                const float4 wv = wr[j];
                s += v[j].x * wv.x + v[j].y * wv.y
                   + v[j].z * wv.z + v[j].w * wv.w;
            }
            acc[oo] = s;
        }
    }

    const int rem = rem0 + px;
#pragma unroll
    for (int oo = 0; oo < 5; ++oo) {
        const int o = og * 5 + oo;
        if (o < 18)
            offs[(b * 18 + o) * HW_ + rem] = acc[oo] + b_off[o];
    }
}

// ---------------------------------------------------------------------------
// Kernel 2: deformable conv + fused BN stats. (R11 structure; occupancy
// bump: launch_bounds(512,8) -> 4 blocks/CU, VGPR cap 64 >= measured 40.)
// ---------------------------------------------------------------------------
__global__ __launch_bounds__(512, 8) void k_deform(
    const float* __restrict__ xt, const float* __restrict__ offs,
    const float* __restrict__ wt, const float* __restrict__ b_def,
    float* __restrict__ y, float* __restrict__ sum_bc,
    float* __restrict__ sumsq_bc)
{
    __shared__ float vlds[128 * 36];           // [px][c] pad 36, 18.4 KB
    const int tid  = threadIdx.x;
    const int px1  = tid >> 2;
    const int g1   = tid & 3;
    const int px2  = tid & 127;
    const int og   = __builtin_amdgcn_readfirstlane(tid >> 7);
    const int lane = tid & 63;

    const int base = swz1152(blockIdx.x) * 128;
    const int b    = base / HW_;
    const int rb   = base - b * HW_;
    const int rem1 = rb + px1;
    const int h    = rem1 / W_;
    const int w    = rem1 - h * W_;
    const float* xg = xt + (size_t)b * HW_ * 32 + g1 * 8;
    const float* ob = offs + b * 18 * HW_ + rem1;

    float acc[16];
#pragma unroll
    for (int q = 0; q < 16; ++q) acc[q] = 0.f;

    auto mk = [&](int kk, float dy, float dx) -> Cr {
        const float py = (float)(h + kk / 3 - 1) + dy;
        const float qx = (float)(w + kk % 3 - 1) + dx;
        const float y0f = floorf(py), x0f = floorf(qx);
        const float wy = py - y0f, wx = qx - x0f;
        const int iy0 = (int)y0f, ix0 = (int)x0f;
        const int iy1 = iy0 + 1,  ix1 = ix0 + 1;
        const float vy0 = (iy0 >= 0 && iy0 < H_) ? 1.f : 0.f;
        const float vy1 = (iy1 >= 0 && iy1 < H_) ? 1.f : 0.f;
        const float vx0 = (ix0 >= 0 && ix0 < W_) ? 1.f : 0.f;
        const float vx1 = (ix1 >= 0 && ix1 < W_) ? 1.f : 0.f;
        Cr c;
        c.w00 = (1.f - wy) * (1.f - wx) * vy0 * vx0;
        c.w01 = (1.f - wy) * wx * vy0 * vx1;
        c.w10 = wy * (1.f - wx) * vy1 * vx0;
        c.w11 = wy * wx * vy1 * vx1;
        const int cy0 = min(max(iy0, 0), H_ - 1), cy1 = min(max(iy1, 0), H_ - 1);
        const int cx0 = min(max(ix0, 0), W_ - 1), cx1 = min(max(ix1, 0), W_ - 1);
        c.o00 = (cy0 * W_ + cx0) * 32; c.o01 = (cy0 * W_ + cx1) * 32;
        c.o10 = (cy1 * W_ + cx0) * 32; c.o11 = (cy1 * W_ + cx1) * 32;
        return c;
    };

    float dy = ob[0], dx = ob[HW_];
    Cr cur = mk(0, dy, dx);
    float4 A0 = *(const float4*)(xg + cur.o00), A1 = *(const float4*)(xg + cur.o00 + 4);
    float4 B0 = *(const float4*)(xg + cur.o01), B1 = *(const float4*)(xg + cur.o01 + 4);
    float4 C0 = *(const float4*)(xg + cur.o10), C1 = *(const float4*)(xg + cur.o10 + 4);
    float4 D0 = *(const float4*)(xg + cur.o11), D1 = *(const float4*)(xg + cur.o11 + 4);
    float ndy = ob[2 * HW_], ndx = ob[3 * HW_];

#pragma unroll 1
    for (int kk = 0; kk < 9; ++kk) {
        __syncthreads();                       // previous phase-2 reads done
        float4 v0, v1;
        v0.x = cur.w00 * A0.x + cur.w01 * B0.x + cur.w10 * C0.x + cur.w11 * D0.x;
        v0.y = cur.w00 * A0.y + cur.w01 * B0.y + cur.w10 * C0.y + cur.w11 * D0.y;
        v0.z = cur.w00 * A0.z + cur.w01 * B0.z + cur.w10 * C0.z + cur.w11 * D0.z;
        v0.w = cur.w00 * A0.w + cur.w01 * B0.w + cur.w10 * C0.w + cur.w11 * D0.w;
        v1.x = cur.w00 * A1.x + cur.w01 * B1.x + cur.w10 * C1.x + cur.w11 * D1.x;
        v1.y = cur.w00 * A1.y + cur.w01 * B1.y + cur.w10 * C1.y + cur.w11 * D1.y;
        v1.z = cur.w00 * A1.z + cur.w01 * B1.z + cur.w10 * C1.z + cur.w11 * D1.z;
        v1.w = cur.w00 * A1.w + cur.w01 * B1.w + cur.w10 * C1.w + cur.w11 * D1.w;
        *(float4*)&vlds[px1 * 36 + g1 * 8]     = v0;
        *(float4*)&vlds[px1 * 36 + g1 * 8 + 4] = v1;

        if (kk < 8) {                          // issue next kk's gathers now
            cur = mk(kk + 1, ndy, ndx);
            A0 = *(const float4*)(xg + cur.o00); A1 = *(const float4*)(xg + cur.o00 + 4);
            B0 = *(const float4*)(xg + cur.o01); B1 = *(const float4*)(xg + cur.o01 + 4);
            C0 = *(const float4*)(xg + cur.o10); C1 = *(const float4*)(xg + cur.o10 + 4);
            D0 = *(const float4*)(xg + cur.o11); D1 = *(const float4*)(xg + cur.o11 + 4);
            if (kk < 7) {
                ndy = ob[(2 * kk + 4) * HW_];
                ndx = ob[(2 * kk + 5) * HW_];
            }
        }
        __syncthreads();                       // v(kk) visible

        const float* wk = wt + (kk << 11) + (og << 4);   // wt[kk][.][16og]
        const float* vp = &vlds[px2 * 36];
#pragma unroll
        for (int j = 0; j < 8; ++j) {
            const float4 vv = *(const float4*)(vp + 4 * j);   // ds_read_b128
            const float vs[4] = {vv.x, vv.y, vv.z, vv.w};
#pragma unroll
            for (int e = 0; e < 4; ++e) {
                const float4* wr = (const float4*)(wk + ((j * 4 + e) << 6));
                const float4 w0 = wr[0], w1 = wr[1], w2 = wr[2], w3 = wr[3];
                const float vc = vs[e];
                acc[ 0] += vc * w0.x; acc[ 1] += vc * w0.y;
                acc[ 2] += vc * w0.z; acc[ 3] += vc * w0.w;
                acc[ 4] += vc * w1.x; acc[ 5] += vc * w1.y;
                acc[ 6] += vc * w1.z; acc[ 7] += vc * w1.w;
                acc[ 8] += vc * w2.x; acc[ 9] += vc * w2.y;
                acc[10] += vc * w2.z; acc[11] += vc * w2.w;
                acc[12] += vc * w3.x; acc[13] += vc * w3.y;
                acc[14] += vc * w3.z; acc[15] += vc * w3.w;
            }
        }
    }

    // bias + store (16 channels for this og, pixel rem2)
    const int rem2 = rb + px2;
    float* yp = y + ((size_t)b * COUT_ + og * 16) * HW_ + rem2;
#pragma unroll
    for (int q = 0; q < 16; ++q) {
        acc[q] += b_def[og * 16 + q];
        yp[q * HW_] = acc[q];
    }

    // fused BN stats: wave = (64 px, one og). Butterfly 16 channels.
    float ls = 0.f, lq = 0.f;
#pragma unroll
    for (int o = 0; o < 16; ++o) {
        float t = acc[o];
        float u = t * t;
#pragma unroll
        for (int s = 32; s; s >>= 1) {
            t += __shfl_xor(t, s, 64);
            u += __shfl_xor(u, s, 64);
        }
        if (lane == o) { ls = t; lq = u; }
    }
    if (lane < 16) {
        atomicAdd(&sum_bc[b * 64 + og * 16 + lane], ls);
        atomicAdd(&sumsq_bc[b * 64 + og * 16 + lane], lq);
    }
}

// ---------------------------------------------------------------------------
// Kernel 3: fused SE-MLP + affine(BN*SE) + ReLU + 2x2 maxpool.
// ---------------------------------------------------------------------------
__global__ __launch_bounds__(256) void k_finish(
    const float* __restrict__ y,
    const float* __restrict__ sum_bc, const float* __restrict__ sumsq_bc,
    const float* __restrict__ gamma, const float* __restrict__ beta,
    const float* __restrict__ fc1_w, const float* __restrict__ fc1_b,
    const float* __restrict__ fc2_w, const float* __restrict__ fc2_b,
    float* __restrict__ out)
{
    __shared__ float sal[256], sbb[256], sin_[256];
    const int tid = threadIdx.x;
    {
        const int b = tid >> 6, c = tid & 63;
        float ch_s = 0.f, ch_q = 0.f;
#pragma unroll
        for (int bb = 0; bb < 4; ++bb) {
            ch_s += sum_bc[bb * 64 + c];
            ch_q += sumsq_bc[bb * 64 + c];
        }
        const float invN = 1.f / (float)(B_ * HW_);
        const float mean = ch_s * invN;
        const float var  = ch_q * invN - mean * mean;
        const float a    = gamma[c] * rsqrtf(var + EPS_);
        const float bi   = beta[c] - mean * a;
        sin_[tid] = a * (sum_bc[tid] * (1.f / (float)HW_)) + bi;
        __syncthreads();
        float hv[4];
#pragma unroll
        for (int j = 0; j < 4; ++j) {
            float hs = fc1_b[j];
            for (int cc = 0; cc < 64; ++cc)
                hs += sin_[b * 64 + cc] * fc1_w[j * 64 + cc];
            hv[j] = fmaxf(hs, 0.f);
        }
        float o = fc2_b[c];
#pragma unroll
        for (int j = 0; j < 4; ++j) o += hv[j] * fc2_w[c * 4 + j];
        const float s = 1.f / (1.f + expf(-o));
        sal[tid] = a * s;
        sbb[tid] = bi * s;
    }
    __syncthreads();

    const int t    = blockIdx.x * 256 + tid;
    const int opix = t * 2;
    const int bc   = opix / (96 * 96);
    const int rem  = opix - bc * (96 * 96);
    const int oh   = rem / 96, ow = rem - oh * 96;   // ow even
    const float al = sal[bc], bb = sbb[bc];
    const float* yp = y + (size_t)bc * HW_ + (2 * oh) * W_ + 2 * ow;
    const float4 r0 = *(const float4*)yp;
    const float4 r1 = *(const float4*)(yp + W_);
    float2 st;
    st.x = fmaxf(fmaxf(fmaxf(fmaf(r0.x, al, bb), fmaf(r0.y, al, bb)),
                       fmaxf(fmaf(r1.x, al, bb), fmaf(r1.y, al, bb))), 0.f);
    st.y = fmaxf(fmaxf(fmaxf(fmaf(r0.z, al, bb), fmaf(r0.w, al, bb)),
                       fmaxf(fmaf(r1.z, al, bb), fmaf(r1.w, al, bb))), 0.f);
    *(float2*)(out + opix) = st;
}

// ---------------------------------------------------------------------------
extern "C" void kernel_launch(void* const* d_in, const int* in_sizes, int n_in,
                              void* d_out, int out_size, void* d_ws, size_t ws_size,
                              hipStream_t stream)
{
    const float* x     = (const float*)d_in[0];
    const float* w_off = (const float*)d_in[1];
    const float* b_off = (const float*)d_in[2];
    const float* w_def = (const float*)d_in[3];
    const float* b_def = (const float*)d_in[4];
    const float* gamma = (const float*)d_in[5];
    const float* beta  = (const float*)d_in[6];
    const float* fc1_w = (const float*)d_in[7];
    const float* fc1_b = (const float*)d_in[8];
    const float* fc2_w = (const float*)d_in[9];
    const float* fc2_b = (const float*)d_in[10];
    float* out = (float*)d_out;

    float* ws   = (float*)d_ws;
    float* offs   = ws;                          // 2,654,208 floats
    float* yb     = offs + 2654208;              // 9,437,184 floats
    float* xt     = yb + 9437184;                // 4,718,592 floats (NHWC x)
    float* wt_def = xt + 4718592;                // 18,432
    float* wt_off = wt_def + 18432;              // 5,760
    float* stats  = wt_off + 5760;               // 1,024
    float* sum_bc   = stats;
    float* sumsq_bc = stats + 256;

    k_pre     <<<dim3(NPIX_ / 256 + 97), dim3(256), 0, stream>>>(
                  x, w_def, w_off, xt, wt_def, wt_off, stats);
    k_conv_off<<<dim3(NPIX_ / 64), dim3(256), 0, stream>>>(xt, wt_off, b_off, offs);
    k_deform  <<<dim3(NPIX_ / 128), dim3(512), 0, stream>>>(xt, offs, wt_def, b_def,
                                                            yb, sum_bc, sumsq_bc);
    k_finish  <<<dim3(B_ * COUT_ * 96 * 96 / 512), dim3(256), 0, stream>>>(
                  yb, sum_bc, sumsq_bc, gamma, beta,
                  fc1_w, fc1_b, fc2_w, fc2_b, out);
}

// Round 13
// 264.662 us; speedup vs baseline: 1.2017x; 1.2017x over previous
//
#include <hip/hip_runtime.h>
#include <math.h>

#define B_    4
#define CIN_  32
#define COUT_ 64
#define H_    192
#define W_    192
#define HW_   (H_ * W_)        // 36864
#define NPIX_ (B_ * HW_)       // 147456
#define EPS_  1e-5f

// XCD-aware swizzle (proven R7: FETCH 300->15.5 MB): XCD k owns a
// contiguous half-image-plane.
static __device__ __forceinline__ int swz1152(int blk) {
    return ((blk & 7) * 144) + (blk >> 3);
}
static __device__ __forceinline__ int swz2304(int blk) {
    return ((blk & 7) * 288) + (blk >> 3);
}

struct Cr { int o00, o01, o10, o11; float w00, w01, w10, w11; };

// ---------------------------------------------------------------------------
// Kernel 0: fused prep. Blocks [0,576): transpose x (NCHW) -> xt (NHWC).
// Blocks [576,673): weight transposes + stats zeroing.
// wt_def[kk][c][o64]; wt_off [kk][o20][c32] (o>=18 zero).
// ---------------------------------------------------------------------------
__global__ __launch_bounds__(256) void k_pre(
    const float* __restrict__ x, const float* __restrict__ w_def,
    const float* __restrict__ w_off, float* __restrict__ xt,
    float* __restrict__ wt_def, float* __restrict__ wt_off,
    float* __restrict__ stats)
{
    if (blockIdx.x < NPIX_ / 256) {
        const int pid = blockIdx.x * 256 + threadIdx.x;
        const int b   = pid / HW_;
        const int rem = pid - b * HW_;
        const float* xb = x + (size_t)b * CIN_ * HW_ + rem;
        float4 v[8];
#pragma unroll
        for (int j = 0; j < 8; ++j) {
            v[j].x = xb[(j * 4 + 0) * HW_];
            v[j].y = xb[(j * 4 + 1) * HW_];
            v[j].z = xb[(j * 4 + 2) * HW_];
            v[j].w = xb[(j * 4 + 3) * HW_];
        }
        float4* dst = (float4*)(xt + (size_t)pid * 32);
#pragma unroll
        for (int j = 0; j < 8; ++j) dst[j] = v[j];
    } else {
        const int i = (blockIdx.x - NPIX_ / 256) * 256 + threadIdx.x;
        if (i < 18432) {                       // wt_def[kk][c][o64]
            const int o  = i & 63;
            const int c  = (i >> 6) & 31;
            const int kk = i >> 11;
            wt_def[i] = w_def[(o * 32 + c) * 9 + kk];
        } else if (i < 18432 + 5760) {         // wt_off[kk][o20][c32]
            const int e  = i - 18432;
            const int c  = e & 31;
            const int t  = e >> 5;
            const int o  = t % 20;
            const int kk = t / 20;
            wt_off[e] = (o < 18) ? w_off[(o * 32 + c) * 9 + kk] : 0.f;
        } else if (i < 18432 + 5760 + 512) {
            stats[i - 18432 - 5760] = 0.f;     // sum_bc + sumsq_bc
        }
    }
}

// ---------------------------------------------------------------------------
// Kernel 1: offsets conv (32 -> 18 ch) via LDS x-tile (regular stencil ->
// zero scattered gathers). Block = 256 thr handles 64 px (192 = 3*64).
// Tile = 3 rows x 66 px x 32 ch float4 planes (25.3 KB), coalesced load.
// Compute: px = tid&63, og = tid>>6 (UNIFORM -> s_load weights), 5 outputs
// per thread; LDS reads lane-stride 16 B (2-way max, free).
// (Kept from R12 — its floor is ~15-20 us; R12's regression was deform
// spill, not this kernel.)
// ---------------------------------------------------------------------------
__global__ __launch_bounds__(256, 6) void k_conv_off(
    const float* __restrict__ xt, const float* __restrict__ wt,
    const float* __restrict__ b_off, float* __restrict__ offs)
{
    __shared__ float4 tile[8][198];            // [ch-quad j][r*66+cc]
    const int tid = threadIdx.x;
    const int px  = tid & 63;
    const int og  = __builtin_amdgcn_readfirstlane(tid >> 6);

    const int blk  = swz2304(blockIdx.x);
    const int base = blk * 64;
    const int b    = base / HW_;
    const int rem0 = base - b * HW_;
    const int h0   = rem0 / W_;
    const int w0   = rem0 - h0 * W_;           // 0, 64, or 128

    const float* xb = xt + (size_t)b * HW_ * 32;
    for (int i = tid; i < 1584; i += 256) {
        const int j   = i & 7;
        const int rec = i >> 3;
        const int r   = rec / 66;
        const int cc  = rec - r * 66;
        const int hc  = min(max(h0 + r - 1, 0), H_ - 1);
        const int wc  = min(max(w0 + cc - 1, 0), W_ - 1);
        tile[j][rec] = *(const float4*)(xb + (hc * W_ + wc) * 32 + j * 4);
    }
    __syncthreads();

    const bool rv0 = (h0 - 1 >= 0), rv2 = (h0 + 1 < H_);
    float acc[5] = {0.f, 0.f, 0.f, 0.f, 0.f};

#pragma unroll 1
    for (int kk = 0; kk < 9; ++kk) {
        const int ky = kk / 3, kx = kk % 3;
        const bool rok = (ky == 0) ? rv0 : ((ky == 2) ? rv2 : true);
        const int wcol = w0 + px + kx - 1;
        const float g = (rok && wcol >= 0 && wcol < W_) ? 1.f : 0.f;
        const int rec = ky * 66 + px + kx;

        float4 v[8];
#pragma unroll
        for (int j = 0; j < 8; ++j) {
            v[j] = tile[j][rec];
            v[j].x *= g; v[j].y *= g; v[j].z *= g; v[j].w *= g;
        }
        const float* wk = wt + (kk * 20 + og * 5) * 32;   // [kk][5og..][c32]
#pragma unroll
        for (int oo = 0; oo < 5; ++oo) {
            const float4* wr = (const float4*)(wk + oo * 32);
            float s = acc[oo];
#pragma unroll
            for (int j = 0; j < 8; ++j) {
                const float4 wv = wr[j];
                s += v[j].x * wv.x + v[j].y * wv.y
                   + v[j].z * wv.z + v[j].w * wv.w;
            }
            acc[oo] = s;
        }
    }

    const int rem = rem0 + px;
#pragma unroll
    for (int oo = 0; oo < 5; ++oo) {
        const int o = og * 5 + oo;
        if (o < 18)
            offs[(b * 18 + o) * HW_ + rem] = acc[oo] + b_off[o];
    }
}

// ---------------------------------------------------------------------------
// Kernel 2: deformable conv + fused BN stats — EXACT R9 form (proven:
// 134 us, FETCH 17.5 MB, WRITE 42.6 MB, VGPR 40, zero spill).
// 512 thr per 128 px; phase 1: thread (px=tid&127, grp=tid>>7) gathers
// channels [8grp,+8) of its pixel's 4 corners, bilinear v[8] -> LDS
// [c][px]; next kk's gathers issued before phase 2. Phase 2: 16 outputs
// [16grp,+16) over 32 LDS channels, s_load weights. (512,6): no spill.
// ---------------------------------------------------------------------------
__global__ __launch_bounds__(512, 6) void k_deform(
    const float* __restrict__ xt, const float* __restrict__ offs,
    const float* __restrict__ wt, const float* __restrict__ b_def,
    float* __restrict__ y, float* __restrict__ sum_bc,
    float* __restrict__ sumsq_bc)
{
    __shared__ float vlds[32 * 128];           // [c][px], 16 KB
    const int tid  = threadIdx.x;
    const int px   = tid & 127;
    const int grp  = __builtin_amdgcn_readfirstlane(tid >> 7);
    const int lane = tid & 63;
    const int pid  = swz1152(blockIdx.x) * 128 + px;
    const int b    = pid / HW_;
    const int rem  = pid - b * HW_;
    const int h    = rem / W_;
    const int w    = rem - h * W_;
    const float* xg = xt + (size_t)b * HW_ * 32 + grp * 8;
    const float* ob = offs + b * 18 * HW_ + rem;

    float acc[16];
#pragma unroll
    for (int q = 0; q < 16; ++q) acc[q] = 0.f;

    auto mk = [&](int kk, float dy, float dx) -> Cr {
        const float py = (float)(h + kk / 3 - 1) + dy;
        const float qx = (float)(w + kk % 3 - 1) + dx;
        const float y0f = floorf(py), x0f = floorf(qx);
        const float wy = py - y0f, wx = qx - x0f;
        const int iy0 = (int)y0f, ix0 = (int)x0f;
        const int iy1 = iy0 + 1,  ix1 = ix0 + 1;
        const float vy0 = (iy0 >= 0 && iy0 < H_) ? 1.f : 0.f;
        const float vy1 = (iy1 >= 0 && iy1 < H_) ? 1.f : 0.f;
        const float vx0 = (ix0 >= 0 && ix0 < W_) ? 1.f : 0.f;
        const float vx1 = (ix1 >= 0 && ix1 < W_) ? 1.f : 0.f;
        Cr c;
        c.w00 = (1.f - wy) * (1.f - wx) * vy0 * vx0;
        c.w01 = (1.f - wy) * wx * vy0 * vx1;
        c.w10 = wy * (1.f - wx) * vy1 * vx0;
        c.w11 = wy * wx * vy1 * vx1;
        const int cy0 = min(max(iy0, 0), H_ - 1), cy1 = min(max(iy1, 0), H_ - 1);
        const int cx0 = min(max(ix0, 0), W_ - 1), cx1 = min(max(ix1, 0), W_ - 1);
        c.o00 = (cy0 * W_ + cx0) * 32; c.o01 = (cy0 * W_ + cx1) * 32;
        c.o10 = (cy1 * W_ + cx0) * 32; c.o11 = (cy1 * W_ + cx1) * 32;
        return c;
    };

    float dy = ob[0], dx = ob[HW_];
    Cr cur = mk(0, dy, dx);
    float4 A0 = *(const float4*)(xg + cur.o00), A1 = *(const float4*)(xg + cur.o00 + 4);
    float4 B0 = *(const float4*)(xg + cur.o01), B1 = *(const float4*)(xg + cur.o01 + 4);
    float4 C0 = *(const float4*)(xg + cur.o10), C1 = *(const float4*)(xg + cur.o10 + 4);
    float4 D0 = *(const float4*)(xg + cur.o11), D1 = *(const float4*)(xg + cur.o11 + 4);
    float ndy = ob[2 * HW_], ndx = ob[3 * HW_];

#pragma unroll 1
    for (int kk = 0; kk < 9; ++kk) {
        __syncthreads();                       // previous phase-2 reads done
        float v[8];
        v[0] = cur.w00 * A0.x + cur.w01 * B0.x + cur.w10 * C0.x + cur.w11 * D0.x;
        v[1] = cur.w00 * A0.y + cur.w01 * B0.y + cur.w10 * C0.y + cur.w11 * D0.y;
        v[2] = cur.w00 * A0.z + cur.w01 * B0.z + cur.w10 * C0.z + cur.w11 * D0.z;
        v[3] = cur.w00 * A0.w + cur.w01 * B0.w + cur.w10 * C0.w + cur.w11 * D0.w;
        v[4] = cur.w00 * A1.x + cur.w01 * B1.x + cur.w10 * C1.x + cur.w11 * D1.x;
        v[5] = cur.w00 * A1.y + cur.w01 * B1.y + cur.w10 * C1.y + cur.w11 * D1.y;
        v[6] = cur.w00 * A1.z + cur.w01 * B1.z + cur.w10 * C1.z + cur.w11 * D1.z;
        v[7] = cur.w00 * A1.w + cur.w01 * B1.w + cur.w10 * C1.w + cur.w11 * D1.w;
#pragma unroll
        for (int j = 0; j < 8; ++j) vlds[(grp * 8 + j) * 128 + px] = v[j];

        if (kk < 8) {                          // issue next kk's gathers now;
            cur = mk(kk + 1, ndy, ndx);        // they fly during phase 2
            A0 = *(const float4*)(xg + cur.o00); A1 = *(const float4*)(xg + cur.o00 + 4);
            B0 = *(const float4*)(xg + cur.o01); B1 = *(const float4*)(xg + cur.o01 + 4);
            C0 = *(const float4*)(xg + cur.o10); C1 = *(const float4*)(xg + cur.o10 + 4);
            D0 = *(const float4*)(xg + cur.o11); D1 = *(const float4*)(xg + cur.o11 + 4);
            if (kk < 7) {
                ndy = ob[(2 * kk + 4) * HW_];
                ndx = ob[(2 * kk + 5) * HW_];
            }
        }
        __syncthreads();                       // v(kk) visible

        const float* wk = wt + (kk << 11) + (grp << 4);   // wt[kk][.][16grp]
#pragma unroll 8
        for (int c = 0; c < 32; ++c) {
            const float vv = vlds[c * 128 + px];
            const float4* wr = (const float4*)(wk + (c << 6));
            const float4 w0 = wr[0], w1 = wr[1], w2 = wr[2], w3 = wr[3];
            acc[ 0] += vv * w0.x; acc[ 1] += vv * w0.y;
            acc[ 2] += vv * w0.z; acc[ 3] += vv * w0.w;
            acc[ 4] += vv * w1.x; acc[ 5] += vv * w1.y;
            acc[ 6] += vv * w1.z; acc[ 7] += vv * w1.w;
            acc[ 8] += vv * w2.x; acc[ 9] += vv * w2.y;
            acc[10] += vv * w2.z; acc[11] += vv * w2.w;
            acc[12] += vv * w3.x; acc[13] += vv * w3.y;
            acc[14] += vv * w3.z; acc[15] += vv * w3.w;
        }
    }

    // bias + store (16 channels for this grp)
    float* yp = y + ((size_t)b * COUT_ + grp * 16) * HW_ + rem;
#pragma unroll
    for (int q = 0; q < 16; ++q) {
        acc[q] += b_def[grp * 16 + q];
        yp[q * HW_] = acc[q];
    }

    // fused BN stats: wave = (64 px, one grp). Butterfly 16 channels.
    float ls = 0.f, lq = 0.f;
#pragma unroll
    for (int o = 0; o < 16; ++o) {
        float t = acc[o];
        float u = t * t;
#pragma unroll
        for (int s = 32; s; s >>= 1) {
            t += __shfl_xor(t, s, 64);
            u += __shfl_xor(u, s, 64);
        }
        if (lane == o) { ls = t; lq = u; }
    }
    if (lane < 16) {
        atomicAdd(&sum_bc[b * 64 + grp * 16 + lane], ls);
        atomicAdd(&sumsq_bc[b * 64 + grp * 16 + lane], lq);
    }
}

// ---------------------------------------------------------------------------
// Kernel 3: fused SE-MLP + affine(BN*SE) + ReLU + 2x2 maxpool.
// ---------------------------------------------------------------------------
__global__ __launch_bounds__(256) void k_finish(
    const float* __restrict__ y,
    const float* __restrict__ sum_bc, const float* __restrict__ sumsq_bc,
    const float* __restrict__ gamma, const float* __restrict__ beta,
    const float* __restrict__ fc1_w, const float* __restrict__ fc1_b,
    const float* __restrict__ fc2_w, const float* __restrict__ fc2_b,
    float* __restrict__ out)
{
    __shared__ float sal[256], sbb[256], sin_[256];
    const int tid = threadIdx.x;
    {
        const int b = tid >> 6, c = tid & 63;
        float ch_s = 0.f, ch_q = 0.f;
#pragma unroll
        for (int bb = 0; bb < 4; ++bb) {
            ch_s += sum_bc[bb * 64 + c];
            ch_q += sumsq_bc[bb * 64 + c];
        }
        const float invN = 1.f / (float)(B_ * HW_);
        const float mean = ch_s * invN;
        const float var  = ch_q * invN - mean * mean;
        const float a    = gamma[c] * rsqrtf(var + EPS_);
        const float bi   = beta[c] - mean * a;
        sin_[tid] = a * (sum_bc[tid] * (1.f / (float)HW_)) + bi;
        __syncthreads();
        float hv[4];
#pragma unroll
        for (int j = 0; j < 4; ++j) {
            float hs = fc1_b[j];
            for (int cc = 0; cc < 64; ++cc)
                hs += sin_[b * 64 + cc] * fc1_w[j * 64 + cc];
            hv[j] = fmaxf(hs, 0.f);
        }
        float o = fc2_b[c];
#pragma unroll
        for (int j = 0; j < 4; ++j) o += hv[j] * fc2_w[c * 4 + j];
        const float s = 1.f / (1.f + expf(-o));
        sal[tid] = a * s;
        sbb[tid] = bi * s;
    }
    __syncthreads();

    const int t    = blockIdx.x * 256 + tid;
    const int opix = t * 2;
    const int bc   = opix / (96 * 96);
    const int rem  = opix - bc * (96 * 96);
    const int oh   = rem / 96, ow = rem - oh * 96;   // ow even
    const float al = sal[bc], bb = sbb[bc];
    const float* yp = y + (size_t)bc * HW_ + (2 * oh) * W_ + 2 * ow;
    const float4 r0 = *(const float4*)yp;
    const float4 r1 = *(const float4*)(yp + W_);
    float2 st;
    st.x = fmaxf(fmaxf(fmaxf(fmaf(r0.x, al, bb), fmaf(r0.y, al, bb)),
                       fmaxf(fmaf(r1.x, al, bb), fmaf(r1.y, al, bb))), 0.f);
    st.y = fmaxf(fmaxf(fmaxf(fmaf(r0.z, al, bb), fmaf(r0.w, al, bb)),
                       fmaxf(fmaf(r1.z, al, bb), fmaf(r1.w, al, bb))), 0.f);
    *(float2*)(out + opix) = st;
}

// ---------------------------------------------------------------------------
extern "C" void kernel_launch(void* const* d_in, const int* in_sizes, int n_in,
                              void* d_out, int out_size, void* d_ws, size_t ws_size,
                              hipStream_t stream)
{
    const float* x     = (const float*)d_in[0];
    const float* w_off = (const float*)d_in[1];
    const float* b_off = (const float*)d_in[2];
    const float* w_def = (const float*)d_in[3];
    const float* b_def = (const float*)d_in[4];
    const float* gamma = (const float*)d_in[5];
    const float* beta  = (const float*)d_in[6];
    const float* fc1_w = (const float*)d_in[7];
    const float* fc1_b = (const float*)d_in[8];
    const float* fc2_w = (const float*)d_in[9];
    const float* fc2_b = (const float*)d_in[10];
    float* out = (float*)d_out;

    float* ws   = (float*)d_ws;
    float* offs   = ws;                          // 2,654,208 floats
    float* yb     = offs + 2654208;              // 9,437,184 floats
    float* xt     = yb + 9437184;                // 4,718,592 floats (NHWC x)
    float* wt_def = xt + 4718592;                // 18,432
    float* wt_off = wt_def + 18432;              // 5,760
    float* stats  = wt_off + 5760;               // 1,024
    float* sum_bc   = stats;
    float* sumsq_bc = stats + 256;

    k_pre     <<<dim3(NPIX_ / 256 + 97), dim3(256), 0, stream>>>(
                  x, w_def, w_off, xt, wt_def, wt_off, stats);
    k_conv_off<<<dim3(NPIX_ / 64), dim3(256), 0, stream>>>(xt, wt_off, b_off, offs);
    k_deform  <<<dim3(NPIX_ / 128), dim3(512), 0, stream>>>(xt, offs, wt_def, b_def,
                                                            yb, sum_bc, sumsq_bc);
    k_finish  <<<dim3(B_ * COUT_ * 96 * 96 / 512), dim3(256), 0, stream>>>(
                  yb, sum_bc, sumsq_bc, gamma, beta,
                  fc1_w, fc1_b, fc2_w, fc2_b, out);
}

// Round 14
// 224.620 us; speedup vs baseline: 1.4159x; 1.1783x over previous
//
#include <hip/hip_runtime.h>
#include <math.h>

#define B_    4
#define CIN_  32
#define COUT_ 64
#define H_    192
#define W_    192
#define HW_   (H_ * W_)        // 36864
#define NPIX_ (B_ * HW_)       // 147456
#define EPS_  1e-5f

// XCD-aware swizzle (proven R7): XCD k owns a contiguous half-image-plane.
static __device__ __forceinline__ int swz2304(int blk) {
    return ((blk & 7) * 288) + (blk >> 3);
}

struct Cr { int o00, o01, o10, o11; float w00, w01, w10, w11; };

// ---------------------------------------------------------------------------
// Kernel 0: fused prep. Blocks [0,576): transpose x (NCHW) -> xt (NHWC).
// Blocks [576,673): weight transposes + stats zeroing.
// wt_def[kk][c][o64]; wt_off [kk][o20][c32] (o>=18 zero).
// ---------------------------------------------------------------------------
__global__ __launch_bounds__(256) void k_pre(
    const float* __restrict__ x, const float* __restrict__ w_def,
    const float* __restrict__ w_off, float* __restrict__ xt,
    float* __restrict__ wt_def, float* __restrict__ wt_off,
    float* __restrict__ stats)
{
    if (blockIdx.x < NPIX_ / 256) {
        const int pid = blockIdx.x * 256 + threadIdx.x;
        const int b   = pid / HW_;
        const int rem = pid - b * HW_;
        const float* xb = x + (size_t)b * CIN_ * HW_ + rem;
        float4 v[8];
#pragma unroll
        for (int j = 0; j < 8; ++j) {
            v[j].x = xb[(j * 4 + 0) * HW_];
            v[j].y = xb[(j * 4 + 1) * HW_];
            v[j].z = xb[(j * 4 + 2) * HW_];
            v[j].w = xb[(j * 4 + 3) * HW_];
        }
        float4* dst = (float4*)(xt + (size_t)pid * 32);
#pragma unroll
        for (int j = 0; j < 8; ++j) dst[j] = v[j];
    } else {
        const int i = (blockIdx.x - NPIX_ / 256) * 256 + threadIdx.x;
        if (i < 18432) {                       // wt_def[kk][c][o64]
            const int o  = i & 63;
            const int c  = (i >> 6) & 31;
            const int kk = i >> 11;
            wt_def[i] = w_def[(o * 32 + c) * 9 + kk];
        } else if (i < 18432 + 5760) {         // wt_off[kk][o20][c32]
            const int e  = i - 18432;
            const int c  = e & 31;
            const int t  = e >> 5;
            const int o  = t % 20;
            const int kk = t / 20;
            wt_off[e] = (o < 18) ? w_off[(o * 32 + c) * 9 + kk] : 0.f;
        } else if (i < 18432 + 5760 + 512) {
            stats[i - 18432 - 5760] = 0.f;     // sum_bc + sumsq_bc
        }
    }
}

// ---------------------------------------------------------------------------
// Kernel 1: FUSED offsets-conv + deformable conv + BN stats.
// Block = 256 thr, 64 px (one row segment; 192 = 3*64). Grid 2304 (9/CU).
//
// Stage A (offsets conv, proven R12/R13 tile form): LDS x-tile 3 rows x
// 66 px x 32 ch (25.3 KB), coalesced load; px=tid&63, og=tid>>6 uniform ->
// s_load weights; 5 outputs/thread -> offlds[20][64] (never to global).
//
// Stage B (deform): tile LDS reused as ping-pong v-buffers vbuf[2][32][64]
// (ONE barrier per kk). Thread (px, og): gathers channels [8og,+8) of its
// pixel's 4 bilinear corners (offsets read from offlds), v[8] -> vbuf;
// phase-2: 16 outputs [16og,+16) over 32 LDS channels, s_load weights.
// Epilogue: bias + y store + per-wave butterfly BN stats.
// (256,6): VGPR cap 85 — the no-spill budget proven by R9/R13.
// ---------------------------------------------------------------------------
__global__ __launch_bounds__(256, 6) void k_fused(
    const float* __restrict__ xt, const float* __restrict__ wto,
    const float* __restrict__ b_off, const float* __restrict__ wtd,
    const float* __restrict__ b_def, float* __restrict__ y,
    float* __restrict__ sum_bc, float* __restrict__ sumsq_bc)
{
    __shared__ __align__(16) float smem[6336];   // 25,344 B: tile, then vbuf
    __shared__ float offlds[20 * 64];            // 5 KB
    float4 (*tile)[198] = (float4(*)[198])smem;  // [ch-quad j][r*66+cc]
    float* vbuf = smem;                          // [2][32][64] after stage A

    const int tid  = threadIdx.x;
    const int px   = tid & 63;
    const int og   = __builtin_amdgcn_readfirstlane(tid >> 6);  // uniform
    const int lane = tid & 63;                   // == px

    const int blk  = swz2304(blockIdx.x);
    const int base = blk * 64;
    const int b    = base / HW_;
    const int rem0 = base - b * HW_;
    const int h0   = rem0 / W_;
    const int w0   = rem0 - h0 * W_;             // 0, 64, or 128
    const float* xb = xt + (size_t)b * HW_ * 32;

    // ---------------- Stage A: offsets conv ----------------
    for (int i = tid; i < 1584; i += 256) {
        const int j   = i & 7;
        const int rec = i >> 3;
        const int r   = rec / 66;
        const int cc  = rec - r * 66;
        const int hc  = min(max(h0 + r - 1, 0), H_ - 1);
        const int wc  = min(max(w0 + cc - 1, 0), W_ - 1);
        tile[j][rec] = *(const float4*)(xb + (hc * W_ + wc) * 32 + j * 4);
    }
    __syncthreads();

    {
        const bool rv0 = (h0 - 1 >= 0), rv2 = (h0 + 1 < H_);
        float acc5[5] = {0.f, 0.f, 0.f, 0.f, 0.f};
#pragma unroll 1
        for (int kk = 0; kk < 9; ++kk) {
            const int ky = kk / 3, kx = kk % 3;
            const bool rok = (ky == 0) ? rv0 : ((ky == 2) ? rv2 : true);
            const int wcol = w0 + px + kx - 1;
            const float g = (rok && wcol >= 0 && wcol < W_) ? 1.f : 0.f;
            const int rec = ky * 66 + px + kx;

            float4 v[8];
#pragma unroll
            for (int j = 0; j < 8; ++j) {
                v[j] = tile[j][rec];
                v[j].x *= g; v[j].y *= g; v[j].z *= g; v[j].w *= g;
            }
            const float* wk = wto + (kk * 20 + og * 5) * 32;
#pragma unroll
            for (int oo = 0; oo < 5; ++oo) {
                const float4* wr = (const float4*)(wk + oo * 32);
                float s = acc5[oo];
#pragma unroll
                for (int j = 0; j < 8; ++j) {
                    const float4 wv = wr[j];
                    s += v[j].x * wv.x + v[j].y * wv.y
                       + v[j].z * wv.z + v[j].w * wv.w;
                }
                acc5[oo] = s;
            }
        }
#pragma unroll
        for (int oo = 0; oo < 5; ++oo) {
            const int o = og * 5 + oo;
            if (o < 18) offlds[o * 64 + px] = acc5[oo] + b_off[o];
        }
    }
    __syncthreads();          // tile dead; offlds ready; vbuf region free

    // ---------------- Stage B: deformable conv ----------------
    const int h = h0;
    const int w = w0 + px;
    const float* xg = xb + og * 8;               // channels [8og, 8og+8)

    float acc[16];
#pragma unroll
    for (int q = 0; q < 16; ++q) acc[q] = 0.f;

    auto mk = [&](int kk) -> Cr {
        const float dy = offlds[(2 * kk) * 64 + px];
        const float dx = offlds[(2 * kk + 1) * 64 + px];
        const float py = (float)(h + kk / 3 - 1) + dy;
        const float qx = (float)(w + kk % 3 - 1) + dx;
        const float y0f = floorf(py), x0f = floorf(qx);
        const float wy = py - y0f, wx = qx - x0f;
        const int iy0 = (int)y0f, ix0 = (int)x0f;
        const int iy1 = iy0 + 1,  ix1 = ix0 + 1;
        const float vy0 = (iy0 >= 0 && iy0 < H_) ? 1.f : 0.f;
        const float vy1 = (iy1 >= 0 && iy1 < H_) ? 1.f : 0.f;
        const float vx0 = (ix0 >= 0 && ix0 < W_) ? 1.f : 0.f;
        const float vx1 = (ix1 >= 0 && ix1 < W_) ? 1.f : 0.f;
        Cr c;
        c.w00 = (1.f - wy) * (1.f - wx) * vy0 * vx0;
        c.w01 = (1.f - wy) * wx * vy0 * vx1;
        c.w10 = wy * (1.f - wx) * vy1 * vx0;
        c.w11 = wy * wx * vy1 * vx1;
        const int cy0 = min(max(iy0, 0), H_ - 1), cy1 = min(max(iy1, 0), H_ - 1);
        const int cx0 = min(max(ix0, 0), W_ - 1), cx1 = min(max(ix1, 0), W_ - 1);
        c.o00 = (cy0 * W_ + cx0) * 32; c.o01 = (cy0 * W_ + cx1) * 32;
        c.o10 = (cy1 * W_ + cx0) * 32; c.o11 = (cy1 * W_ + cx1) * 32;
        return c;
    };

    // prologue: corners(0) -> v(0) -> vbuf[0]
    {
        Cr c0 = mk(0);
        float4 A0 = *(const float4*)(xg + c0.o00), A1 = *(const float4*)(xg + c0.o00 + 4);
        float4 B0 = *(const float4*)(xg + c0.o01), B1 = *(const float4*)(xg + c0.o01 + 4);
        float4 C0 = *(const float4*)(xg + c0.o10), C1 = *(const float4*)(xg + c0.o10 + 4);
        float4 D0 = *(const float4*)(xg + c0.o11), D1 = *(const float4*)(xg + c0.o11 + 4);
        float v[8];
        v[0] = c0.w00 * A0.x + c0.w01 * B0.x + c0.w10 * C0.x + c0.w11 * D0.x;
        v[1] = c0.w00 * A0.y + c0.w01 * B0.y + c0.w10 * C0.y + c0.w11 * D0.y;
        v[2] = c0.w00 * A0.z + c0.w01 * B0.z + c0.w10 * C0.z + c0.w11 * D0.z;
        v[3] = c0.w00 * A0.w + c0.w01 * B0.w + c0.w10 * C0.w + c0.w11 * D0.w;
        v[4] = c0.w00 * A1.x + c0.w01 * B1.x + c0.w10 * C1.x + c0.w11 * D1.x;
        v[5] = c0.w00 * A1.y + c0.w01 * B1.y + c0.w10 * C1.y + c0.w11 * D1.y;
        v[6] = c0.w00 * A1.z + c0.w01 * B1.z + c0.w10 * C1.z + c0.w11 * D1.z;
        v[7] = c0.w00 * A1.w + c0.w01 * B1.w + c0.w10 * C1.w + c0.w11 * D1.w;
#pragma unroll
        for (int j = 0; j < 8; ++j) vbuf[(og * 8 + j) * 64 + px] = v[j];
    }
    __syncthreads();

#pragma unroll 1
    for (int kk = 0; kk < 9; ++kk) {
        // issue next kk's gathers now — they fly during phase 2
        Cr nx; float4 A0, A1, B0, B1, C0, C1, D0, D1;
        if (kk < 8) {
            nx = mk(kk + 1);
            A0 = *(const float4*)(xg + nx.o00); A1 = *(const float4*)(xg + nx.o00 + 4);
            B0 = *(const float4*)(xg + nx.o01); B1 = *(const float4*)(xg + nx.o01 + 4);
            C0 = *(const float4*)(xg + nx.o10); C1 = *(const float4*)(xg + nx.o10 + 4);
            D0 = *(const float4*)(xg + nx.o11); D1 = *(const float4*)(xg + nx.o11 + 4);
        }

        // phase 2: 16 outputs from vbuf[kk&1]
        const float* vp = vbuf + (kk & 1) * 2048;
        const float* wk = wtd + (kk << 11) + (og << 4);   // wt[kk][.][16og]
#pragma unroll 8
        for (int c = 0; c < 32; ++c) {
            const float vv = vp[c * 64 + px];
            const float4* wr = (const float4*)(wk + (c << 6));
            const float4 w0 = wr[0], w1 = wr[1], w2 = wr[2], w3 = wr[3];
            acc[ 0] += vv * w0.x; acc[ 1] += vv * w0.y;
            acc[ 2] += vv * w0.z; acc[ 3] += vv * w0.w;
            acc[ 4] += vv * w1.x; acc[ 5] += vv * w1.y;
            acc[ 6] += vv * w1.z; acc[ 7] += vv * w1.w;
            acc[ 8] += vv * w2.x; acc[ 9] += vv * w2.y;
            acc[10] += vv * w2.z; acc[11] += vv * w2.w;
            acc[12] += vv * w3.x; acc[13] += vv * w3.y;
            acc[14] += vv * w3.z; acc[15] += vv * w3.w;
        }

        if (kk < 8) {                      // bilinear(kk+1) -> other buffer
            float v[8];
            v[0] = nx.w00 * A0.x + nx.w01 * B0.x + nx.w10 * C0.x + nx.w11 * D0.x;
            v[1] = nx.w00 * A0.y + nx.w01 * B0.y + nx.w10 * C0.y + nx.w11 * D0.y;
            v[2] = nx.w00 * A0.z + nx.w01 * B0.z + nx.w10 * C0.z + nx.w11 * D0.z;
            v[3] = nx.w00 * A0.w + nx.w01 * B0.w + nx.w10 * C0.w + nx.w11 * D0.w;
            v[4] = nx.w00 * A1.x + nx.w01 * B1.x + nx.w10 * C1.x + nx.w11 * D1.x;
            v[5] = nx.w00 * A1.y + nx.w01 * B1.y + nx.w10 * C1.y + nx.w11 * D1.y;
            v[6] = nx.w00 * A1.z + nx.w01 * B1.z + nx.w10 * C1.z + nx.w11 * D1.z;
            v[7] = nx.w00 * A1.w + nx.w01 * B1.w + nx.w10 * C1.w + nx.w11 * D1.w;
            float* wp = vbuf + ((kk + 1) & 1) * 2048;
#pragma unroll
            for (int j = 0; j < 8; ++j) wp[(og * 8 + j) * 64 + px] = v[j];
            __syncthreads();               // vbuf[(kk+1)&1] ready; reads of
        }                                  // vbuf[kk&1] done before rewrite
    }

    // bias + store (16 channels for this og)
    const int rem = rem0 + px;
    float* yp = y + ((size_t)b * COUT_ + og * 16) * HW_ + rem;
#pragma unroll
    for (int q = 0; q < 16; ++q) {
        acc[q] += b_def[og * 16 + q];
        yp[q * HW_] = acc[q];
    }

    // fused BN stats: wave = (64 px, one og). Butterfly 16 channels.
    float ls = 0.f, lq = 0.f;
#pragma unroll
    for (int o = 0; o < 16; ++o) {
        float t = acc[o];
        float u = t * t;
#pragma unroll
        for (int s = 32; s; s >>= 1) {
            t += __shfl_xor(t, s, 64);
            u += __shfl_xor(u, s, 64);
        }
        if (lane == o) { ls = t; lq = u; }
    }
    if (lane < 16) {
        atomicAdd(&sum_bc[b * 64 + og * 16 + lane], ls);
        atomicAdd(&sumsq_bc[b * 64 + og * 16 + lane], lq);
    }
}

// ---------------------------------------------------------------------------
// Kernel 2: fused SE-MLP + affine(BN*SE) + ReLU + 2x2 maxpool.
// ---------------------------------------------------------------------------
__global__ __launch_bounds__(256) void k_finish(
    const float* __restrict__ y,
    const float* __restrict__ sum_bc, const float* __restrict__ sumsq_bc,
    const float* __restrict__ gamma, const float* __restrict__ beta,
    const float* __restrict__ fc1_w, const float* __restrict__ fc1_b,
    const float* __restrict__ fc2_w, const float* __restrict__ fc2_b,
    float* __restrict__ out)
{
    __shared__ float sal[256], sbb[256], sin_[256];
    const int tid = threadIdx.x;
    {
        const int b = tid >> 6, c = tid & 63;
        float ch_s = 0.f, ch_q = 0.f;
#pragma unroll
        for (int bb = 0; bb < 4; ++bb) {
            ch_s += sum_bc[bb * 64 + c];
            ch_q += sumsq_bc[bb * 64 + c];
        }
        const float invN = 1.f / (float)(B_ * HW_);
        const float mean = ch_s * invN;
        const float var  = ch_q * invN - mean * mean;
        const float a    = gamma[c] * rsqrtf(var + EPS_);
        const float bi   = beta[c] - mean * a;
        sin_[tid] = a * (sum_bc[tid] * (1.f / (float)HW_)) + bi;
        __syncthreads();
        float hv[4];
#pragma unroll
        for (int j = 0; j < 4; ++j) {
            float hs = fc1_b[j];
            for (int cc = 0; cc < 64; ++cc)
                hs += sin_[b * 64 + cc] * fc1_w[j * 64 + cc];
            hv[j] = fmaxf(hs, 0.f);
        }
        float o = fc2_b[c];
#pragma unroll
        for (int j = 0; j < 4; ++j) o += hv[j] * fc2_w[c * 4 + j];
        const float s = 1.f / (1.f + expf(-o));
        sal[tid] = a * s;
        sbb[tid] = bi * s;
    }
    __syncthreads();

    const int t    = blockIdx.x * 256 + tid;
    const int opix = t * 2;
    const int bc   = opix / (96 * 96);
    const int rem  = opix - bc * (96 * 96);
    const int oh   = rem / 96, ow = rem - oh * 96;   // ow even
    const float al = sal[bc], bb = sbb[bc];
    const float* yp = y + (size_t)bc * HW_ + (2 * oh) * W_ + 2 * ow;
    const float4 r0 = *(const float4*)yp;
    const float4 r1 = *(const float4*)(yp + W_);
    float2 st;
    st.x = fmaxf(fmaxf(fmaxf(fmaf(r0.x, al, bb), fmaf(r0.y, al, bb)),
                       fmaxf(fmaf(r1.x, al, bb), fmaf(r1.y, al, bb))), 0.f);
    st.y = fmaxf(fmaxf(fmaxf(fmaf(r0.z, al, bb), fmaf(r0.w, al, bb)),
                       fmaxf(fmaf(r1.z, al, bb), fmaf(r1.w, al, bb))), 0.f);
    *(float2*)(out + opix) = st;
}

// ---------------------------------------------------------------------------
extern "C" void kernel_launch(void* const* d_in, const int* in_sizes, int n_in,
                              void* d_out, int out_size, void* d_ws, size_t ws_size,
                              hipStream_t stream)
{
    const float* x     = (const float*)d_in[0];
    const float* w_off = (const float*)d_in[1];
    const float* b_off = (const float*)d_in[2];
    const float* w_def = (const float*)d_in[3];
    const float* b_def = (const float*)d_in[4];
    const float* gamma = (const float*)d_in[5];
    const float* beta  = (const float*)d_in[6];
    const float* fc1_w = (const float*)d_in[7];
    const float* fc1_b = (const float*)d_in[8];
    const float* fc2_w = (const float*)d_in[9];
    const float* fc2_b = (const float*)d_in[10];
    float* out = (float*)d_out;

    float* ws   = (float*)d_ws;
    float* yb     = ws;                          // 9,437,184 floats
    float* xt     = yb + 9437184;                // 4,718,592 floats (NHWC x)
    float* wt_def = xt + 4718592;                // 18,432
    float* wt_off = wt_def + 18432;              // 5,760
    float* stats  = wt_off + 5760;               // 1,024
    float* sum_bc   = stats;
    float* sumsq_bc = stats + 256;

    k_pre   <<<dim3(NPIX_ / 256 + 97), dim3(256), 0, stream>>>(
                x, w_def, w_off, xt, wt_def, wt_off, stats);
    k_fused <<<dim3(NPIX_ / 64), dim3(256), 0, stream>>>(
                xt, wt_off, b_off, wt_def, b_def, yb, sum_bc, sumsq_bc);
    k_finish<<<dim3(B_ * COUT_ * 96 * 96 / 512), dim3(256), 0, stream>>>(
                yb, sum_bc, sumsq_bc, gamma, beta,
                fc1_w, fc1_b, fc2_w, fc2_b, out);
}

// Round 15
// 222.848 us; speedup vs baseline: 1.4272x; 1.0079x over previous
//
#include <hip/hip_runtime.h>
#include <math.h>

#define B_    4
#define CIN_  32
#define COUT_ 64
#define H_    192
#define W_    192
#define HW_   (H_ * W_)        // 36864
#define NPIX_ (B_ * HW_)       // 147456
#define EPS_  1e-5f

// XCD-aware swizzle (proven R7): XCD k owns a contiguous half-image-plane.
static __device__ __forceinline__ int swz2304(int blk) {
    return ((blk & 7) * 288) + (blk >> 3);
}

struct Cr { int o00, o01, o10, o11; float w00, w01, w10, w11; };

// ---------------------------------------------------------------------------
// Kernel 0: fused prep.
// Blocks [0,576): transpose x (NCHW) -> xt (NHWC) via LDS staging —
//   loads: per channel, 256 consecutive floats (coalesced); LDS [c][257]
//   (pad -> write conflict-free, read <=2-way);
//   stores: 8 consecutive float4/thread (4 KB contiguous per wave instr).
// Blocks [576,673): weight transposes + stats zeroing.
// wt_def[kk][c][o64]; wt_off [kk][o20][c32] (o>=18 zero).
// ---------------------------------------------------------------------------
__global__ __launch_bounds__(256) void k_pre(
    const float* __restrict__ x, const float* __restrict__ w_def,
    const float* __restrict__ w_off, float* __restrict__ xt,
    float* __restrict__ wt_def, float* __restrict__ wt_off,
    float* __restrict__ stats)
{
    if (blockIdx.x < NPIX_ / 256) {
        __shared__ float lds[32 * 257];
        const int tid  = threadIdx.x;
        const int pid0 = blockIdx.x * 256;
        const int b    = pid0 / HW_;           // blocks never straddle b
        const int rem0 = pid0 - b * HW_;
        const float* xb = x + (size_t)b * CIN_ * HW_ + rem0;

#pragma unroll
        for (int c = 0; c < 32; ++c)
            lds[c * 257 + tid] = xb[c * HW_ + tid];
        __syncthreads();

        float4* dst = (float4*)(xt + (size_t)pid0 * 32);
#pragma unroll
        for (int i = 0; i < 8; ++i) {
            const int idx = i * 256 + tid;     // consecutive across lanes
            const int px  = idx >> 3;
            const int q   = idx & 7;
            float4 v;
            v.x = lds[(q * 4 + 0) * 257 + px];
            v.y = lds[(q * 4 + 1) * 257 + px];
            v.z = lds[(q * 4 + 2) * 257 + px];
            v.w = lds[(q * 4 + 3) * 257 + px];
            dst[idx] = v;
        }
    } else {
        const int i = (blockIdx.x - NPIX_ / 256) * 256 + threadIdx.x;
        if (i < 18432) {                       // wt_def[kk][c][o64]
            const int o  = i & 63;
            const int c  = (i >> 6) & 31;
            const int kk = i >> 11;
            wt_def[i] = w_def[(o * 32 + c) * 9 + kk];
        } else if (i < 18432 + 5760) {         // wt_off[kk][o20][c32]
            const int e  = i - 18432;
            const int c  = e & 31;
            const int t  = e >> 5;
            const int o  = t % 20;
            const int kk = t / 20;
            wt_off[e] = (o < 18) ? w_off[(o * 32 + c) * 9 + kk] : 0.f;
        } else if (i < 18432 + 5760 + 512) {
            stats[i - 18432 - 5760] = 0.f;     // sum_bc + sumsq_bc
        }
    }
}

// ---------------------------------------------------------------------------
// Kernel 1: FUSED offsets-conv + deformable conv + BN stats.
// (Unchanged from R14 — 141 us, VGPR 44, zero spill, VALUBusy 60%.)
// Block = 256 thr, 64 px. Stage A: LDS x-tile offsets conv -> offlds.
// Stage B: ping-pong vbuf deform, one barrier per kk; s_load weights.
// ---------------------------------------------------------------------------
__global__ __launch_bounds__(256, 6) void k_fused(
    const float* __restrict__ xt, const float* __restrict__ wto,
    const float* __restrict__ b_off, const float* __restrict__ wtd,
    const float* __restrict__ b_def, float* __restrict__ y,
    float* __restrict__ sum_bc, float* __restrict__ sumsq_bc)
{
    __shared__ __align__(16) float smem[6336];   // 25,344 B: tile, then vbuf
    __shared__ float offlds[20 * 64];            // 5 KB
    float4 (*tile)[198] = (float4(*)[198])smem;  // [ch-quad j][r*66+cc]
    float* vbuf = smem;                          // [2][32][64] after stage A

    const int tid  = threadIdx.x;
    const int px   = tid & 63;
    const int og   = __builtin_amdgcn_readfirstlane(tid >> 6);  // uniform
    const int lane = tid & 63;                   // == px

    const int blk  = swz2304(blockIdx.x);
    const int base = blk * 64;
    const int b    = base / HW_;
    const int rem0 = base - b * HW_;
    const int h0   = rem0 / W_;
    const int w0   = rem0 - h0 * W_;             // 0, 64, or 128
    const float* xb = xt + (size_t)b * HW_ * 32;

    // ---------------- Stage A: offsets conv ----------------
    for (int i = tid; i < 1584; i += 256) {
        const int j   = i & 7;
        const int rec = i >> 3;
        const int r   = rec / 66;
        const int cc  = rec - r * 66;
        const int hc  = min(max(h0 + r - 1, 0), H_ - 1);
        const int wc  = min(max(w0 + cc - 1, 0), W_ - 1);
        tile[j][rec] = *(const float4*)(xb + (hc * W_ + wc) * 32 + j * 4);
    }
    __syncthreads();

    {
        const bool rv0 = (h0 - 1 >= 0), rv2 = (h0 + 1 < H_);
        float acc5[5] = {0.f, 0.f, 0.f, 0.f, 0.f};
#pragma unroll 1
        for (int kk = 0; kk < 9; ++kk) {
            const int ky = kk / 3, kx = kk % 3;
            const bool rok = (ky == 0) ? rv0 : ((ky == 2) ? rv2 : true);
            const int wcol = w0 + px + kx - 1;
            const float g = (rok && wcol >= 0 && wcol < W_) ? 1.f : 0.f;
            const int rec = ky * 66 + px + kx;

            float4 v[8];
#pragma unroll
            for (int j = 0; j < 8; ++j) {
                v[j] = tile[j][rec];
                v[j].x *= g; v[j].y *= g; v[j].z *= g; v[j].w *= g;
            }
            const float* wk = wto + (kk * 20 + og * 5) * 32;
#pragma unroll
            for (int oo = 0; oo < 5; ++oo) {
                const float4* wr = (const float4*)(wk + oo * 32);
                float s = acc5[oo];
#pragma unroll
                for (int j = 0; j < 8; ++j) {
                    const float4 wv = wr[j];
                    s += v[j].x * wv.x + v[j].y * wv.y
                       + v[j].z * wv.z + v[j].w * wv.w;
                }
                acc5[oo] = s;
            }
        }
#pragma unroll
        for (int oo = 0; oo < 5; ++oo) {
            const int o = og * 5 + oo;
            if (o < 18) offlds[o * 64 + px] = acc5[oo] + b_off[o];
        }
    }
    __syncthreads();          // tile dead; offlds ready; vbuf region free

    // ---------------- Stage B: deformable conv ----------------
    const int h = h0;
    const int w = w0 + px;
    const float* xg = xb + og * 8;               // channels [8og, 8og+8)

    float acc[16];
#pragma unroll
    for (int q = 0; q < 16; ++q) acc[q] = 0.f;

    auto mk = [&](int kk) -> Cr {
        const float dy = offlds[(2 * kk) * 64 + px];
        const float dx = offlds[(2 * kk + 1) * 64 + px];
        const float py = (float)(h + kk / 3 - 1) + dy;
        const float qx = (float)(w + kk % 3 - 1) + dx;
        const float y0f = floorf(py), x0f = floorf(qx);
        const float wy = py - y0f, wx = qx - x0f;
        const int iy0 = (int)y0f, ix0 = (int)x0f;
        const int iy1 = iy0 + 1,  ix1 = ix0 + 1;
        const float vy0 = (iy0 >= 0 && iy0 < H_) ? 1.f : 0.f;
        const float vy1 = (iy1 >= 0 && iy1 < H_) ? 1.f : 0.f;
        const float vx0 = (ix0 >= 0 && ix0 < W_) ? 1.f : 0.f;
        const float vx1 = (ix1 >= 0 && ix1 < W_) ? 1.f : 0.f;
        Cr c;
        c.w00 = (1.f - wy) * (1.f - wx) * vy0 * vx0;
        c.w01 = (1.f - wy) * wx * vy0 * vx1;
        c.w10 = wy * (1.f - wx) * vy1 * vx0;
        c.w11 = wy * wx * vy1 * vx1;
        const int cy0 = min(max(iy0, 0), H_ - 1), cy1 = min(max(iy1, 0), H_ - 1);
        const int cx0 = min(max(ix0, 0), W_ - 1), cx1 = min(max(ix1, 0), W_ - 1);
        c.o00 = (cy0 * W_ + cx0) * 32; c.o01 = (cy0 * W_ + cx1) * 32;
        c.o10 = (cy1 * W_ + cx0) * 32; c.o11 = (cy1 * W_ + cx1) * 32;
        return c;
    };

    // prologue: corners(0) -> v(0) -> vbuf[0]
    {
        Cr c0 = mk(0);
        float4 A0 = *(const float4*)(xg + c0.o00), A1 = *(const float4*)(xg + c0.o00 + 4);
        float4 B0 = *(const float4*)(xg + c0.o01), B1 = *(const float4*)(xg + c0.o01 + 4);
        float4 C0 = *(const float4*)(xg + c0.o10), C1 = *(const float4*)(xg + c0.o10 + 4);
        float4 D0 = *(const float4*)(xg + c0.o11), D1 = *(const float4*)(xg + c0.o11 + 4);
        float v[8];
        v[0] = c0.w00 * A0.x + c0.w01 * B0.x + c0.w10 * C0.x + c0.w11 * D0.x;
        v[1] = c0.w00 * A0.y + c0.w01 * B0.y + c0.w10 * C0.y + c0.w11 * D0.y;
        v[2] = c0.w00 * A0.z + c0.w01 * B0.z + c0.w10 * C0.z + c0.w11 * D0.z;
        v[3] = c0.w00 * A0.w + c0.w01 * B0.w + c0.w10 * C0.w + c0.w11 * D0.w;
        v[4] = c0.w00 * A1.x + c0.w01 * B1.x + c0.w10 * C1.x + c0.w11 * D1.x;
        v[5] = c0.w00 * A1.y + c0.w01 * B1.y + c0.w10 * C1.y + c0.w11 * D1.y;
        v[6] = c0.w00 * A1.z + c0.w01 * B1.z + c0.w10 * C1.z + c0.w11 * D1.z;
        v[7] = c0.w00 * A1.w + c0.w01 * B1.w + c0.w10 * C1.w + c0.w11 * D1.w;
#pragma unroll
        for (int j = 0; j < 8; ++j) vbuf[(og * 8 + j) * 64 + px] = v[j];
    }
    __syncthreads();

#pragma unroll 1
    for (int kk = 0; kk < 9; ++kk) {
        // issue next kk's gathers now — they fly during phase 2
        Cr nx; float4 A0, A1, B0, B1, C0, C1, D0, D1;
        if (kk < 8) {
            nx = mk(kk + 1);
            A0 = *(const float4*)(xg + nx.o00); A1 = *(const float4*)(xg + nx.o00 + 4);
            B0 = *(const float4*)(xg + nx.o01); B1 = *(const float4*)(xg + nx.o01 + 4);
            C0 = *(const float4*)(xg + nx.o10); C1 = *(const float4*)(xg + nx.o10 + 4);
            D0 = *(const float4*)(xg + nx.o11); D1 = *(const float4*)(xg + nx.o11 + 4);
        }

        // phase 2: 16 outputs from vbuf[kk&1]
        const float* vp = vbuf + (kk & 1) * 2048;
        const float* wk = wtd + (kk << 11) + (og << 4);   // wt[kk][.][16og]
#pragma unroll 8
        for (int c = 0; c < 32; ++c) {
            const float vv = vp[c * 64 + px];
            const float4* wr = (const float4*)(wk + (c << 6));
            const float4 w0 = wr[0], w1 = wr[1], w2 = wr[2], w3 = wr[3];
            acc[ 0] += vv * w0.x; acc[ 1] += vv * w0.y;
            acc[ 2] += vv * w0.z; acc[ 3] += vv * w0.w;
            acc[ 4] += vv * w1.x; acc[ 5] += vv * w1.y;
            acc[ 6] += vv * w1.z; acc[ 7] += vv * w1.w;
            acc[ 8] += vv * w2.x; acc[ 9] += vv * w2.y;
            acc[10] += vv * w2.z; acc[11] += vv * w2.w;
            acc[12] += vv * w3.x; acc[13] += vv * w3.y;
            acc[14] += vv * w3.z; acc[15] += vv * w3.w;
        }

        if (kk < 8) {                      // bilinear(kk+1) -> other buffer
            float v[8];
            v[0] = nx.w00 * A0.x + nx.w01 * B0.x + nx.w10 * C0.x + nx.w11 * D0.x;
            v[1] = nx.w00 * A0.y + nx.w01 * B0.y + nx.w10 * C0.y + nx.w11 * D0.y;
            v[2] = nx.w00 * A0.z + nx.w01 * B0.z + nx.w10 * C0.z + nx.w11 * D0.z;
            v[3] = nx.w00 * A0.w + nx.w01 * B0.w + nx.w10 * C0.w + nx.w11 * D0.w;
            v[4] = nx.w00 * A1.x + nx.w01 * B1.x + nx.w10 * C1.x + nx.w11 * D1.x;
            v[5] = nx.w00 * A1.y + nx.w01 * B1.y + nx.w10 * C1.y + nx.w11 * D1.y;
            v[6] = nx.w00 * A1.z + nx.w01 * B1.z + nx.w10 * C1.z + nx.w11 * D1.z;
            v[7] = nx.w00 * A1.w + nx.w01 * B1.w + nx.w10 * C1.w + nx.w11 * D1.w;
            float* wp = vbuf + ((kk + 1) & 1) * 2048;
#pragma unroll
            for (int j = 0; j < 8; ++j) wp[(og * 8 + j) * 64 + px] = v[j];
            __syncthreads();               // vbuf[(kk+1)&1] ready; reads of
        }                                  // vbuf[kk&1] done before rewrite
    }

    // bias + store (16 channels for this og)
    const int rem = rem0 + px;
    float* yp = y + ((size_t)b * COUT_ + og * 16) * HW_ + rem;
#pragma unroll
    for (int q = 0; q < 16; ++q) {
        acc[q] += b_def[og * 16 + q];
        yp[q * HW_] = acc[q];
    }

    // fused BN stats: wave = (64 px, one og). Butterfly 16 channels.
    float ls = 0.f, lq = 0.f;
#pragma unroll
    for (int o = 0; o < 16; ++o) {
        float t = acc[o];
        float u = t * t;
#pragma unroll
        for (int s = 32; s; s >>= 1) {
            t += __shfl_xor(t, s, 64);
            u += __shfl_xor(u, s, 64);
        }
        if (lane == o) { ls = t; lq = u; }
    }
    if (lane < 16) {
        atomicAdd(&sum_bc[b * 64 + og * 16 + lane], ls);
        atomicAdd(&sumsq_bc[b * 64 + og * 16 + lane], lq);
    }
}

// ---------------------------------------------------------------------------
// Kernel 2: fused SE-MLP + affine(BN*SE) + ReLU + 2x2 maxpool.
// ---------------------------------------------------------------------------
__global__ __launch_bounds__(256) void k_finish(
    const float* __restrict__ y,
    const float* __restrict__ sum_bc, const float* __restrict__ sumsq_bc,
    const float* __restrict__ gamma, const float* __restrict__ beta,
    const float* __restrict__ fc1_w, const float* __restrict__ fc1_b,
    const float* __restrict__ fc2_w, const float* __restrict__ fc2_b,
    float* __restrict__ out)
{
    __shared__ float sal[256], sbb[256], sin_[256];
    const int tid = threadIdx.x;
    {
        const int b = tid >> 6, c = tid & 63;
        float ch_s = 0.f, ch_q = 0.f;
#pragma unroll
        for (int bb = 0; bb < 4; ++bb) {
            ch_s += sum_bc[bb * 64 + c];
            ch_q += sumsq_bc[bb * 64 + c];
        }
        const float invN = 1.f / (float)(B_ * HW_);
        const float mean = ch_s * invN;
        const float var  = ch_q * invN - mean * mean;
        const float a    = gamma[c] * rsqrtf(var + EPS_);
        const float bi   = beta[c] - mean * a;
        sin_[tid] = a * (sum_bc[tid] * (1.f / (float)HW_)) + bi;
        __syncthreads();
        float hv[4];
#pragma unroll
        for (int j = 0; j < 4; ++j) {
            float hs = fc1_b[j];
            for (int cc = 0; cc < 64; ++cc)
                hs += sin_[b * 64 + cc] * fc1_w[j * 64 + cc];
            hv[j] = fmaxf(hs, 0.f);
        }
        float o = fc2_b[c];
#pragma unroll
        for (int j = 0; j < 4; ++j) o += hv[j] * fc2_w[c * 4 + j];
        const float s = 1.f / (1.f + expf(-o));
        sal[tid] = a * s;
        sbb[tid] = bi * s;
    }
    __syncthreads();

    const int t    = blockIdx.x * 256 + tid;
    const int opix = t * 2;
    const int bc   = opix / (96 * 96);
    const int rem  = opix - bc * (96 * 96);
    const int oh   = rem / 96, ow = rem - oh * 96;   // ow even
    const float al = sal[bc], bb = sbb[bc];
    const float* yp = y + (size_t)bc * HW_ + (2 * oh) * W_ + 2 * ow;
    const float4 r0 = *(const float4*)yp;
    const float4 r1 = *(const float4*)(yp + W_);
    float2 st;
    st.x = fmaxf(fmaxf(fmaxf(fmaf(r0.x, al, bb), fmaf(r0.y, al, bb)),
                       fmaxf(fmaf(r1.x, al, bb), fmaf(r1.y, al, bb))), 0.f);
    st.y = fmaxf(fmaxf(fmaxf(fmaf(r0.z, al, bb), fmaf(r0.w, al, bb)),
                       fmaxf(fmaf(r1.z, al, bb), fmaf(r1.w, al, bb))), 0.f);
    *(float2*)(out + opix) = st;
}

// ---------------------------------------------------------------------------
extern "C" void kernel_launch(void* const* d_in, const int* in_sizes, int n_in,
                              void* d_out, int out_size, void* d_ws, size_t ws_size,
                              hipStream_t stream)
{
    const float* x     = (const float*)d_in[0];
    const float* w_off = (const float*)d_in[1];
    const float* b_off = (const float*)d_in[2];
    const float* w_def = (const float*)d_in[3];
    const float* b_def = (const float*)d_in[4];
    const float* gamma = (const float*)d_in[5];
    const float* beta  = (const float*)d_in[6];
    const float* fc1_w = (const float*)d_in[7];
    const float* fc1_b = (const float*)d_in[8];
    const float* fc2_w = (const float*)d_in[9];
    const float* fc2_b = (const float*)d_in[10];
    float* out = (float*)d_out;

    float* ws   = (float*)d_ws;
    float* yb     = ws;                          // 9,437,184 floats
    float* xt     = yb + 9437184;                // 4,718,592 floats (NHWC x)
    float* wt_def = xt + 4718592;                // 18,432
    float* wt_off = wt_def + 18432;              // 5,760
    float* stats  = wt_off + 5760;               // 1,024
    float* sum_bc   = stats;
    float* sumsq_bc = stats + 256;

    k_pre   <<<dim3(NPIX_ / 256 + 97), dim3(256), 0, stream>>>(
                x, w_def, w_off, xt, wt_def, wt_off, stats);
    k_fused <<<dim3(NPIX_ / 64), dim3(256), 0, stream>>>(
                xt, wt_off, b_off, wt_def, b_def, yb, sum_bc, sumsq_bc);
    k_finish<<<dim3(B_ * COUT_ * 96 * 96 / 512), dim3(256), 0, stream>>>(
                yb, sum_bc, sumsq_bc, gamma, beta,
                fc1_w, fc1_b, fc2_w, fc2_b, out);
}